// Round 1
// baseline (10190.313 us; speedup 1.0000x reference)
//
#include <hip/hip_runtime.h>
#include <math.h>

#define T_ 512
#define B_ 64
#define I_ 512
#define H_ 512
#define G_ 2048   // 4*H
#define K_ 1024   // I + H

typedef __bf16 bf16x8 __attribute__((ext_vector_type(8)));
typedef float f32x4 __attribute__((ext_vector_type(4)));

// Workspace layout (bytes):
//   Whi bf16 [G_][K_]  : 4 MB   (hi part of [W_ih | W_hh])
//   Wlo bf16 [G_][K_]  : 4 MB   (lo residual, bf16(w - hi))
//   bias f32 [G_]      : 8 KB   (b_ih + b_hh)
//   c    f32 [B_][H_]  : 128 KB (cell state)
#define OFF_WHI  ((size_t)0)
#define OFF_WLO  ((size_t)G_ * K_ * 2)
#define OFF_BIAS (OFF_WLO + (size_t)G_ * K_ * 2)
#define OFF_C    (OFF_BIAS + (size_t)G_ * 4)

__global__ void prep_kernel(const float* __restrict__ W_ih, const float* __restrict__ W_hh,
                            const float* __restrict__ b_ih, const float* __restrict__ b_hh,
                            char* __restrict__ ws) {
    __bf16* Whi = (__bf16*)(ws + OFF_WHI);
    __bf16* Wlo = (__bf16*)(ws + OFF_WLO);
    float* bias = (float*)(ws + OFF_BIAS);
    int idx = blockIdx.x * 256 + threadIdx.x;   // over G_*K_ = 2M elements
    int g = idx >> 10;                          // /K_
    int k = idx & (K_ - 1);
    float v = (k < I_) ? W_ih[g * I_ + k] : W_hh[g * H_ + (k - I_)];
    __bf16 hi = (__bf16)v;
    Whi[idx] = hi;
    Wlo[idx] = (__bf16)(v - (float)hi);
    if (idx < G_) bias[idx] = b_ih[idx] + b_hh[idx];
}

#define ZP 136   // 128 K-chunk + 8 pad (row = 272 B: 16B-aligned, bank-staggered)

// One timestep: gates = [x_t | h_prev] @ [W_ih | W_hh]^T + bias, then cell update.
// Grid: 32 WGs x 256 threads. WG wg owns hidden units [wg*16, wg*16+16).
// Wave w (0..3) = gate type (i,f,g,o): computes rows w*512 + wg*16 + (0..15),
// all 64 batches (4 MFMA N-tiles), K=1024 in 8 LDS-staged chunks of 128.
__launch_bounds__(256, 1)
__global__ void lstm_step(const float* __restrict__ input, const float* __restrict__ h0,
                          float* __restrict__ out, char* __restrict__ ws, int t) {
    __shared__ __bf16 zhi[B_][ZP];
    __shared__ __bf16 zlo[B_][ZP];
    __shared__ float gl[4][16][65];   // [gate][unit][batch], +1 pad vs 64

    const __bf16* Whi = (const __bf16*)(ws + OFF_WHI);
    const __bf16* Wlo = (const __bf16*)(ws + OFF_WLO);
    const float* bias = (const float*)(ws + OFF_BIAS);
    float* c = (float*)(ws + OFF_C);

    const float* x_t = input + (size_t)t * (B_ * I_);
    const float* h_prev = (t == T_ - 1) ? h0 : (out + (size_t)(t + 1) * (B_ * H_));

    const int tid = threadIdx.x;
    const int wave = tid >> 6;      // gate type
    const int lane = tid & 63;
    const int l16 = lane & 15;
    const int quad = lane >> 4;
    const int wg = blockIdx.x;

    // A-operand: A[m = lane&15][k = quad*8 + j], row-major W, k contiguous
    const size_t arow = (size_t)(wave * H_ + wg * 16 + l16) * K_ + quad * 8;
    const __bf16* Ahi = Whi + arow;
    const __bf16* Alo = Wlo + arow;

    f32x4 acc[4] = {{0,0,0,0},{0,0,0,0},{0,0,0,0},{0,0,0,0}};

    for (int cch = 0; cch < 8; ++cch) {
        const int kk = cch * 128;
        __syncthreads();   // previous chunk's compute done before overwrite
        // stage z[64][128] hi/lo: 1024 8-elem chunks, 4 per thread, coalesced
        #pragma unroll
        for (int it = 0; it < 4; ++it) {
            int chunk = it * 256 + tid;
            int b = chunk >> 4;
            int kc = (chunk & 15) << 3;
            int k = kk + kc;   // chunk never straddles x/h boundary (128 | 512)
            const float* src = (k < I_) ? (x_t + b * I_ + k) : (h_prev + b * H_ + (k - I_));
            float4 v0 = *(const float4*)src;
            float4 v1 = *(const float4*)(src + 4);
            float vv[8] = {v0.x, v0.y, v0.z, v0.w, v1.x, v1.y, v1.z, v1.w};
            bf16x8 hi, lo;
            #pragma unroll
            for (int j = 0; j < 8; ++j) {
                __bf16 h8 = (__bf16)vv[j];
                hi[j] = h8;
                lo[j] = (__bf16)(vv[j] - (float)h8);
            }
            *(bf16x8*)&zhi[b][kc] = hi;
            *(bf16x8*)&zlo[b][kc] = lo;
        }
        __syncthreads();
        #pragma unroll
        for (int ks = 0; ks < 4; ++ks) {
            bf16x8 ahi = *(const bf16x8*)(Ahi + kk + ks * 32);
            bf16x8 alo = *(const bf16x8*)(Alo + kk + ks * 32);
            #pragma unroll
            for (int nt = 0; nt < 4; ++nt) {
                bf16x8 bhi = *(const bf16x8*)&zhi[nt * 16 + l16][ks * 32 + quad * 8];
                bf16x8 blo = *(const bf16x8*)&zlo[nt * 16 + l16][ks * 32 + quad * 8];
                acc[nt] = __builtin_amdgcn_mfma_f32_16x16x32_bf16(ahi, bhi, acc[nt], 0, 0, 0);
                acc[nt] = __builtin_amdgcn_mfma_f32_16x16x32_bf16(alo, bhi, acc[nt], 0, 0, 0);
                acc[nt] = __builtin_amdgcn_mfma_f32_16x16x32_bf16(ahi, blo, acc[nt], 0, 0, 0);
            }
        }
    }

    // C/D layout: col(batch) = lane&15 (+16*nt), row(unit) = quad*4 + reg
    #pragma unroll
    for (int r = 0; r < 4; ++r) {
        #pragma unroll
        for (int nt = 0; nt < 4; ++nt) {
            gl[wave][quad * 4 + r][nt * 16 + l16] = acc[nt][r];
        }
    }
    __syncthreads();

    // cell update: 16 units x 64 batches = 1024 cells, 4 per thread
    float* outt = out + (size_t)t * (B_ * H_);
    #pragma unroll
    for (int rep = 0; rep < 4; ++rep) {
        int ci = rep * 256 + tid;
        int b = ci >> 4;
        int u = ci & 15;
        int hu = wg * 16 + u;
        float ig = gl[0][u][b] + bias[hu];
        float fg = gl[1][u][b] + bias[H_ + hu];
        float gg = gl[2][u][b] + bias[2 * H_ + hu];
        float og = gl[3][u][b] + bias[3 * H_ + hu];
        ig = 1.f / (1.f + __expf(-ig));
        fg = 1.f / (1.f + __expf(-fg));
        gg = tanhf(gg);
        og = 1.f / (1.f + __expf(-og));
        float cn = fg * c[b * H_ + hu] + ig * gg;
        c[b * H_ + hu] = cn;
        outt[b * H_ + hu] = og * tanhf(cn);
    }
}

__global__ void finalize_kernel(float* __restrict__ out, const char* __restrict__ ws) {
    const float* c = (const float*)(ws + OFF_C);
    int i = blockIdx.x * 256 + threadIdx.x;   // over B_*H_
    out[(size_t)T_ * B_ * H_ + i] = out[i];                 // h_f = outputs[0]
    out[(size_t)T_ * B_ * H_ + B_ * H_ + i] = c[i];         // c_f
}

extern "C" void kernel_launch(void* const* d_in, const int* in_sizes, int n_in,
                              void* d_out, int out_size, void* d_ws, size_t ws_size,
                              hipStream_t stream) {
    const float* input = (const float*)d_in[0];
    const float* h0   = (const float*)d_in[1];
    const float* c0   = (const float*)d_in[2];
    const float* W_ih = (const float*)d_in[3];
    const float* W_hh = (const float*)d_in[4];
    const float* b_ih = (const float*)d_in[5];
    const float* b_hh = (const float*)d_in[6];
    float* out = (float*)d_out;
    char* ws = (char*)d_ws;

    prep_kernel<<<(G_ * K_) / 256, 256, 0, stream>>>(W_ih, W_hh, b_ih, b_hh, ws);
    hipMemcpyAsync(ws + OFF_C, c0, (size_t)B_ * H_ * sizeof(float),
                   hipMemcpyDeviceToDevice, stream);
    for (int t = T_ - 1; t >= 0; --t) {
        lstm_step<<<H_ / 16, 256, 0, stream>>>(input, h0, out, ws, t);
    }
    finalize_kernel<<<(B_ * H_) / 256, 256, 0, stream>>>(out, ws);
}